// Round 12
// baseline (422.731 us; speedup 1.0000x reference)
//
#include <hip/hip_runtime.h>
#include <hip/hip_bf16.h>

// Problem constants
#define NB     8
#define NPTS   4096
#define DIMC   64
#define KNN_K  8
#define NBLK   12
#define NREP   8      // stats replicas (atomic de-contention)

typedef __attribute__((ext_vector_type(8))) short short8;   // 8 bf16 = 4 VGPR
typedef __attribute__((ext_vector_type(4))) float f32x4;    // MFMA acc

// Dekker split: v = hi + lo with hi = bf16-truncate(v); v - hi is EXACT in
// fp32 (Sterbenz); lo is the bf16-truncation of the remainder.
__device__ __forceinline__ void bsplit(float v, unsigned short& h, unsigned short& l) {
    unsigned b = __float_as_uint(v);
    h = (unsigned short)(b >> 16);
    float hf = __uint_as_float(b & 0xFFFF0000u);
    float lf = v - hf;                       // exact
    l = (unsigned short)(__float_as_uint(lf) >> 16);
}

// ---------------------------------------------------------------------------
// Kernel 0: precompute (x,y,z,|x|^2) per point, zero the 13 stats stages,
// AND pre-split W/9 into bf16 hi/lo planes (once per layer, layout [o][d],
// layer stride 8192 ushorts: whi_t = wq + t*8192, wlo_t = whi_t + 4096).
// Folding the 1/9 into W here replaces the per-gather mean (exact algebra:
// W*mean_j(h_j) == sum_j h_j*(W/9); single fp rounding either way).
// Grid: 192 WGs x 256 = 49152 threads.
// ---------------------------------------------------------------------------
__global__ __launch_bounds__(256) void prep_kernel(
        const float* __restrict__ xyz, float4* __restrict__ pts4g,
        float* __restrict__ stats, const float* __restrict__ conv_w,
        unsigned short* __restrict__ wq) {
#pragma clang fp contract(off)
    int g = blockIdx.x * 256 + threadIdx.x;      // 0..49151
    if (g < 13 * NREP * 128) stats[g] = 0.0f;
    {   // W split: t = g>>12, rem = o*64+d (reads coalesced)
        int t = g >> 12, rem = g & 4095;
        float wv = conv_w[g] * (1.0f / 9.0f);
        unsigned short h, l;
        bsplit(wv, h, l);
        wq[(t << 13) + rem]        = h;
        wq[(t << 13) + 4096 + rem] = l;
    }
    if (g < 32768) {
        int b = g >> 12, j = g & 4095;
        const float* xb = xyz + (size_t)b * 3 * NPTS;
        float x = xb[j];
        float y = xb[NPTS + j];
        float z = xb[2 * NPTS + j];
        float sq = (x * x + y * y) + z * z;
        pts4g[g] = make_float4(x, y, z, sq);
    }
}

// ---------------------------------------------------------------------------
// Kernel 1: transpose fp32 points [b][d][n] -> point-major P0[b][n][d],
// fused with stats[0] accumulation. XCD-affine: b = blockIdx & 7.
// Grid: 512 WGs, 256 threads.
// ---------------------------------------------------------------------------
__global__ __launch_bounds__(256) void cast_kernel(
        const float* __restrict__ pts,
        float* __restrict__ P0, float* __restrict__ stats0) {
    __shared__ __align__(16) float tr[64 * 65];      // [d][n] transpose tile (+1 pad)
    __shared__ float slotA[4 * 64], slotB[4 * 64];
    int wg = blockIdx.x;
    int b = wg & 7;                  // XCD affinity
    int n0 = (wg >> 3) << 6;
    int rep = (wg >> 3) & (NREP - 1);
    int tid = threadIdx.x;
    int lane6 = tid & 63;
    int grp = tid >> 6;              // 0..3

    #pragma unroll
    for (int k = 0; k < 16; ++k) {
        int d = grp + (k << 2);
        float v = pts[(((size_t)((b << 6) + d)) << 12) + n0 + lane6];
        tr[d * 65 + lane6] = v;
    }
    __syncthreads();
    int c = lane6;
    float s = 0.0f, s2 = 0.0f;
    #pragma unroll
    for (int k = 0; k < 16; ++k) {
        int p = grp + (k << 2);
        float v = tr[c * 65 + p];
        P0[((size_t)((b << 12) + n0 + p)) * 64 + c] = v;
        s += v; s2 += v * v;
    }
    slotA[grp * 64 + c] = s;
    slotB[grp * 64 + c] = s2;
    __syncthreads();
    if (tid < 64) {
        float t = slotA[tid] + slotA[64 + tid] + slotA[128 + tid] + slotA[192 + tid];
        atomicAdd(&stats0[rep * 128 + tid], t);
    } else if (tid < 128) {
        int cc = tid - 64;
        float t = slotB[cc] + slotB[64 + cc] + slotB[128 + cc] + slotB[192 + cc];
        atomicAdd(&stats0[rep * 128 + 64 + cc], t);
    }
}

// ---------------------------------------------------------------------------
// Kernel 2: brute-force 8-NN — EXACT R5 form (verified, 111-114 us).
// Scalar-fetch via readfirstlane; no LDS candidate staging; bit-exact d2;
// unique f64 keys (idx in low 12 mantissa bits).
// Grid: 8 b x 32 q-tiles of 128 = 256 WGs, 512 threads.
// ---------------------------------------------------------------------------
#define INS(KEY) do { \
    double key = (KEY); \
    double n0 = fmin(k0, key); \
    double n1 = fmin(k1, fmax(k0, key)); \
    double n2 = fmin(k2, fmax(k1, key)); \
    double n3 = fmin(k3, fmax(k2, key)); \
    double n4 = fmin(k4, fmax(k3, key)); \
    double n5 = fmin(k5, fmax(k4, key)); \
    double n6 = fmin(k6, fmax(k5, key)); \
    double n7 = fmin(k7, fmax(k6, key)); \
    k0 = n0; k1 = n1; k2 = n2; k3 = n3; \
    k4 = n4; k5 = n5; k6 = n6; k7 = n7; } while (0)

__global__ __launch_bounds__(512) void knn_kernel(
        const float4* __restrict__ pts4g, int* __restrict__ idx) {
#pragma clang fp contract(off)
    __shared__ double stash[4 * 9 * 128];            // 36 KB
    int wg = blockIdx.x;
    int b = wg >> 5;
    int q0 = (wg & 31) << 7;
    int tid = threadIdx.x;                           // 0..511

    int lane  = tid & 63;
    int wave  = tid >> 6;            // 0..7
    int chunk = wave & 3;
    int qgrp  = wave >> 2;           // 0..1
    int q_l   = (qgrp << 6) | lane;  // 0..127

    const float4* cb = pts4g + ((size_t)b << 12);
    float4 qp = cb[q0 + q_l];

    double k0, k1, k2, k3, k4, k5, k6, k7;
    k0 = k1 = k2 = k3 = k4 = k5 = k6 = k7 = __builtin_inf();
    float bd7f = 3.4e38f;

    int chu = __builtin_amdgcn_readfirstlane(chunk);
    const float4* cc = cb + ((size_t)chu << 10);     // this wave's 1024-cand window
    int jg0 = chu << 10;                             // global candidate index base

    // --- direct phase: first 128 candidates of the chunk, unconditional ---
    for (int jo = 0; jo < 128; jo += 8) {
        float d2v[8];
        #pragma unroll
        for (int u = 0; u < 8; ++u) {
            float4 p = cc[jo + u];                   // uniform -> s_load
            float dot = (qp.x * p.x + qp.y * p.y) + qp.z * p.z;
            d2v[u] = (qp.w - 2.0f * dot) + p.w;
        }
        #pragma unroll
        for (int u = 0; u < 8; ++u) {
            unsigned long long kb =
                __double_as_longlong((double)d2v[u]) |
                (unsigned long long)(jg0 + jo + u);
            INS(__longlong_as_double(kb));
        }
    }
    bd7f = (float)k7;    // exact: idx bits << half-ulp of f32

    // --- queued phase: branchless hitmask + wave drain ---
    for (int jo = 128; jo < 1024; jo += 8) {
        float d2v[8];
        unsigned hm = 0u;
        #pragma unroll
        for (int u = 0; u < 8; ++u) {
            float4 p = cc[jo + u];                   // uniform -> s_load
            float dot = (qp.x * p.x + qp.y * p.y) + qp.z * p.z;
            float d2 = (qp.w - 2.0f * dot) + p.w;
            d2v[u] = d2;
            hm |= (d2 < bd7f) ? (1u << u) : 0u;
        }
        while (__any(hm != 0u)) {
            if (hm) {
                int u = __builtin_ctz(hm);
                hm &= hm - 1u;
                float t0 = (u & 1) ? d2v[1] : d2v[0];
                float t1 = (u & 1) ? d2v[3] : d2v[2];
                float t2 = (u & 1) ? d2v[5] : d2v[4];
                float t3 = (u & 1) ? d2v[7] : d2v[6];
                float s0 = (u & 2) ? t1 : t0;
                float s1 = (u & 2) ? t3 : t2;
                float d2 = (u & 4) ? s1 : s0;
                unsigned long long kb =
                    __double_as_longlong((double)d2) |
                    (unsigned long long)(jg0 + jo + u);
                INS(__longlong_as_double(kb));
            }
        }
        bd7f = (float)k7;
    }

    {
        double* S = &stash[(chunk * 9) * 128 + q_l];
        S[0 * 128] = k0; S[1 * 128] = k1; S[2 * 128] = k2; S[3 * 128] = k3;
        S[4 * 128] = k4; S[5 * 128] = k5; S[6 * 128] = k6; S[7 * 128] = k7;
        S[8 * 128] = __builtin_inf();    // merge guard
    }
    __syncthreads();

    // 4-way merge per query by key (threads 0..127)
    if (tid < 128) {
        int h0 = 0, h1 = 0, h2 = 0, h3 = 0;
        int* op = idx + ((size_t)(b * NPTS + q0 + tid)) * 8;
        #pragma unroll
        for (int t = 0; t < 8; ++t) {
            double b0 = stash[(0 * 9 + h0) * 128 + tid];
            double b1 = stash[(1 * 9 + h1) * 128 + tid];
            double b2 = stash[(2 * 9 + h2) * 128 + tid];
            double b3 = stash[(3 * 9 + h3) * 128 + tid];
            double best = b0; int bc = 0;
            if (b1 < best) { best = b1; bc = 1; }
            if (b2 < best) { best = b2; bc = 2; }
            if (b3 < best) { best = b3; bc = 3; }
            h0 += (bc == 0); h1 += (bc == 1);
            h2 += (bc == 2); h3 += (bc == 3);
            op[t] = (int)(__double_as_longlong(best) & 0xFFFULL);
        }
    }
}

// ---------------------------------------------------------------------------
// Kernel 2b (x12): h = LReLU(BN_t(P_t)) precompute, split-bf16 hi/lo planes.
// Elementwise, fused with the replica-summed BN affine. The block kernel
// then consumes h directly as MFMA A-fragments — the gather phase (9x
// BN/LReLU recompute + LDS staging + barrier) disappears from the blocks.
// Grid: 512 WGs (64-pt tiles x 8 b, XCD-affine), 256 threads.
// ---------------------------------------------------------------------------
__global__ __launch_bounds__(256) void h_kernel(
        const float* __restrict__ P, const float* __restrict__ statsIn,
        const float* __restrict__ Gp, const float* __restrict__ Betap,
        unsigned short* __restrict__ hH, unsigned short* __restrict__ hL) {
    __shared__ float scale_l[64], shift_l[64];
    int wg = blockIdx.x;
    int b = wg & 7;
    int n0 = (wg >> 3) << 6;
    int tid = threadIdx.x;

    if (tid < 64) {
        int c = tid;
        float sum = 0.0f, sumsq = 0.0f;
        #pragma unroll
        for (int r = 0; r < NREP; ++r) {
            sum   += statsIn[r * 128 + c];
            sumsq += statsIn[r * 128 + 64 + c];
        }
        float mean = sum * (1.0f / 32768.0f);
        float var  = sumsq * (1.0f / 32768.0f) - mean * mean;
        float rs   = 1.0f / sqrtf(var + 1e-5f);
        float sc   = Gp[c] * rs;
        scale_l[c] = sc;
        shift_l[c] = Betap[c] - mean * sc;
    }
    __syncthreads();

    const float4* P4 = (const float4*)(P + (((size_t)(b << 12) + n0) << 6));
    ushort4* h4 = (ushort4*)(hH + (((size_t)(b << 12) + n0) << 6));
    ushort4* l4 = (ushort4*)(hL + (((size_t)(b << 12) + n0) << 6));
    #pragma unroll
    for (int k = 0; k < 4; ++k) {
        int lin = tid + (k << 8);            // float4 id, 0..1023
        int c4 = (lin & 15) << 2;
        float4 v = P4[lin];
        float hx = v.x * scale_l[c4 + 0] + shift_l[c4 + 0];
        float hy = v.y * scale_l[c4 + 1] + shift_l[c4 + 1];
        float hz = v.z * scale_l[c4 + 2] + shift_l[c4 + 2];
        float hw = v.w * scale_l[c4 + 3] + shift_l[c4 + 3];
        hx = fmaxf(hx, 0.01f * hx); hy = fmaxf(hy, 0.01f * hy);
        hz = fmaxf(hz, 0.01f * hz); hw = fmaxf(hw, 0.01f * hw);
        unsigned short ax, ay, az, aw, bx, by, bz, bw;
        bsplit(hx, ax, bx); bsplit(hy, ay, by);
        bsplit(hz, az, bz); bsplit(hw, aw, bw);
        h4[lin] = make_ushort4(ax, ay, az, aw);
        l4[lin] = make_ushort4(bx, by, bz, bw);
    }
}

// ---------------------------------------------------------------------------
// Kernel 3 (x12): one residual block as a PURE MFMA GEMM over K' = 9*64:
// out[pt][o] = sum_{j=0..8} h_j[pt] . (W/9)[o] + b[o] + P[pt][o].
// A-fragments load DIRECTLY from the global h hi/lo planes (16 B contiguous
// per lane per K-step; j = s>>1 uniform per step; rows from idxl). B-frags
// (pre-split W/9 from ws) cycle with period 2 -> all 16 held in VGPRs.
// No gather phase, no BN in-kernel, one barrier total. Fragment pattern is
// byte-identical to the verified R9 mapping (A row = lane&15, k-slot
// 8*(lane>>4), D row = 4g+reg), stride 64 instead of 72.
// Grid: 512 WGs (64-pt tiles x 8 b, XCD-affine), 256 threads. LDS ~21 KB.
// ---------------------------------------------------------------------------
__global__ __launch_bounds__(256) void block_kernel(
        const float* __restrict__ Pin, float* __restrict__ Pout,
        float* __restrict__ statsOut,
        const unsigned short* __restrict__ whl, const float* __restrict__ Bp,
        const int* __restrict__ gidx,
        const unsigned short* __restrict__ hH, const unsigned short* __restrict__ hL,
        float* __restrict__ dout, int last) {
    __shared__ __align__(16) int   idxl[64 * 8];
    __shared__ float slot[4 * 128];
    __shared__ __align__(16) float stage[64 * 65];   // last-block transpose

    int wg = blockIdx.x;
    int b = wg & 7;                  // XCD affinity
    int n0 = (wg >> 3) << 6;
    int rep = (wg >> 3) & (NREP - 1);
    int tid = threadIdx.x;

    if (tid < 128) {
        ((int4*)idxl)[tid] = ((const int4*)(gidx + ((size_t)(b * NPTS + n0)) * 8))[tid];
    }
    __syncthreads();

    int lane = tid & 63;
    int w    = tid >> 6;             // 0..3: pt-quarter
    int g    = lane >> 4;            // k-group
    int c    = lane & 15;
    int ptl  = (w << 4) + c;         // A-row (local pt)

    // neighbor rows (global row within batch): [self, idx0..idx7]
    int r[9];
    r[0] = n0 + ptl;
    #pragma unroll
    for (int j = 1; j < 9; ++j) r[j] = idxl[ptl * 8 + (j - 1)];

    const unsigned short* hHb = hH + ((size_t)(b << 12) << 6);
    const unsigned short* hLb = hL + ((size_t)(b << 12) << 6);
    const unsigned short* whi = whl;            // (W/9) hi, [o][d]
    const unsigned short* wlo = whl + 4096;     // (W/9) lo

    // B-fragments: 4 o-tiles x 2 parities x {hi,lo}, resident in VGPRs
    short8 bh[4][2], bl[4][2];
    #pragma unroll
    for (int ot = 0; ot < 4; ++ot) {
        int co = (ot << 4) + c;
        #pragma unroll
        for (int p = 0; p < 2; ++p) {
            bh[ot][p] = *(const short8*)&whi[(co << 6) + (p << 5) + (g << 3)];
            bl[ot][p] = *(const short8*)&wlo[(co << 6) + (p << 5) + (g << 3)];
        }
    }

    f32x4 acc[4];
    #pragma unroll
    for (int ot = 0; ot < 4; ++ot) acc[ot] = (f32x4){0.f, 0.f, 0.f, 0.f};

    // K' = 576 in 18 steps of 32; step s reads neighbor j = s>>1, parity s&1
    #pragma unroll
    for (int s = 0; s < 18; ++s) {
        int j = s >> 1, p = s & 1;
        int off = (r[j] << 6) + (p << 5) + (g << 3);
        short8 ah = *(const short8*)&hHb[off];
        short8 al = *(const short8*)&hLb[off];
        #pragma unroll
        for (int ot = 0; ot < 4; ++ot) {
            acc[ot] = __builtin_amdgcn_mfma_f32_16x16x32_bf16(ah, bh[ot][p], acc[ot], 0, 0, 0);
            acc[ot] = __builtin_amdgcn_mfma_f32_16x16x32_bf16(ah, bl[ot][p], acc[ot], 0, 0, 0);
            acc[ot] = __builtin_amdgcn_mfma_f32_16x16x32_bf16(al, bh[ot][p], acc[ot], 0, 0, 0);
        }
    }

    // --- epilogue: + bias + residual; D lane holds col=16ot+c, row=4g+jj ---
    const float* Pb = Pin + (((size_t)b) << 18);
    #pragma unroll
    for (int ot = 0; ot < 4; ++ot) {
        int co = (ot << 4) + c;
        float bv = Bp[co];
        #pragma unroll
        for (int jj = 0; jj < 4; ++jj) {
            int ptd = (w << 4) + (g << 2) + jj;          // local D-row
            acc[ot][jj] += bv + Pb[(((size_t)(n0 + ptd)) << 6) + co];
        }
    }

    if (!last) {
        float* PbOut = Pout + ((((size_t)b) << 12) + n0) * 64;
        #pragma unroll
        for (int jj = 0; jj < 4; ++jj) {
            int ptd = (w << 4) + (g << 2) + jj;
            #pragma unroll
            for (int ot = 0; ot < 4; ++ot)
                PbOut[(size_t)ptd * 64 + (ot << 4) + c] = acc[ot][jj];
        }

        // --- stats: j-sum (4 rows) then xor over g -> wave col-sums ---
        float sv[4], qv[4];
        #pragma unroll
        for (int ot = 0; ot < 4; ++ot) {
            float s = 0.f, q = 0.f;
            #pragma unroll
            for (int jj = 0; jj < 4; ++jj) {
                float v = acc[ot][jj];
                s += v; q += v * v;
            }
            sv[ot] = s; qv[ot] = q;
        }
        #pragma unroll
        for (int m = 16; m <= 32; m <<= 1) {
            #pragma unroll
            for (int ot = 0; ot < 4; ++ot) {
                sv[ot] += __shfl_xor(sv[ot], m, 64);
                qv[ot] += __shfl_xor(qv[ot], m, 64);
            }
        }
        if (lane < 16) {
            #pragma unroll
            for (int ot = 0; ot < 4; ++ot) {
                slot[w * 128 + (ot << 4) + lane]      = sv[ot];
                slot[w * 128 + 64 + (ot << 4) + lane] = qv[ot];
            }
        }
        __syncthreads();
        if (tid < 128) {
            float t = slot[tid] + slot[128 + tid] + slot[256 + tid] + slot[384 + tid];
            atomicAdd(&statsOut[rep * 128 + tid], t);
        }
    } else {
        #pragma unroll
        for (int ot = 0; ot < 4; ++ot) {
            int co = (ot << 4) + c;
            #pragma unroll
            for (int jj = 0; jj < 4; ++jj)
                stage[co * 65 + (w << 4) + (g << 2) + jj] = acc[ot][jj];
        }
        __syncthreads();
        #pragma unroll
        for (int k = 0; k < 16; ++k) {
            int lin = tid + (k << 8);
            int o = lin >> 6, pt = lin & 63;
            dout[(((size_t)((b << 6) + o)) << 12) + n0 + pt] = stage[o * 65 + pt];
        }
    }
}

// ---------------------------------------------------------------------------
extern "C" void kernel_launch(void* const* d_in, const int* in_sizes, int n_in,
                              void* d_out, int out_size, void* d_ws, size_t ws_size,
                              hipStream_t stream) {
    const float* xyz    = (const float*)d_in[0];
    const float* pts    = (const float*)d_in[1];
    const float* conv_w = (const float*)d_in[2];
    const float* conv_b = (const float*)d_in[3];
    const float* gamma  = (const float*)d_in[4];
    const float* beta   = (const float*)d_in[5];
    float* out = (float*)d_out;

    char* ws = (char*)d_ws;
    float*          P0    = (float*)(ws);                                 //  8 MB
    float*          P1    = (float*)(ws + (size_t)8 * 1024 * 1024);       //  8 MB
    int*            idx   = (int*)  (ws + (size_t)16 * 1024 * 1024);      //  1 MB
    float*          stats = (float*)(ws + (size_t)17 * 1024 * 1024);      // 52 KB
    float4*         pts4g = (float4*)(ws + (size_t)18 * 1024 * 1024);     // 512 KB
    unsigned short* wq    = (unsigned short*)(ws + (size_t)18 * 1024 * 1024 + 512 * 1024); // 192 KB
    unsigned short* hH    = (unsigned short*)(ws + (size_t)19 * 1024 * 1024);  // 4 MB
    unsigned short* hL    = (unsigned short*)(ws + (size_t)23 * 1024 * 1024);  // 4 MB

    prep_kernel<<<192, 256, 0, stream>>>(xyz, pts4g, stats, conv_w, wq);
    cast_kernel<<<512, 256, 0, stream>>>(pts, P0, stats);
    knn_kernel<<<256, 512, 0, stream>>>(pts4g, idx);

    float* Pbuf[2] = {P0, P1};
    for (int t = 0; t < NBLK; ++t) {
        h_kernel<<<512, 256, 0, stream>>>(
            Pbuf[t & 1], stats + (size_t)t * NREP * 128,
            gamma + (size_t)t * 64, beta + (size_t)t * 64, hH, hL);
        block_kernel<<<512, 256, 0, stream>>>(
            Pbuf[t & 1], Pbuf[(t + 1) & 1],
            stats + (size_t)(t + 1) * NREP * 128,
            wq + (size_t)t * 8192, conv_b + (size_t)t * 64,
            idx, hH, hL, out, (t == NBLK - 1) ? 1 : 0);
    }
}

// Round 13
// 284.912 us; speedup vs baseline: 1.4837x; 1.4837x over previous
//
#include <hip/hip_runtime.h>
#include <hip/hip_bf16.h>

// Problem constants
#define NB     8
#define NPTS   4096
#define DIMC   64
#define KNN_K  8
#define NBLK   12
#define NREP   8      // stats replicas (atomic de-contention)

typedef __attribute__((ext_vector_type(8))) short short8;   // 8 bf16 = 4 VGPR
typedef __attribute__((ext_vector_type(4))) float f32x4;    // MFMA acc

// Dekker split: v = hi + lo with hi = bf16-truncate(v); v - hi is EXACT in
// fp32 (Sterbenz: hi has v's sign/exponent, |v-hi| < ulp_bf16(v)); lo is the
// bf16-truncation of the remainder. Combined precision ~16 mantissa bits.
__device__ __forceinline__ void bsplit(float v, unsigned short& h, unsigned short& l) {
    unsigned b = __float_as_uint(v);
    h = (unsigned short)(b >> 16);
    float hf = __uint_as_float(b & 0xFFFF0000u);
    float lf = v - hf;                       // exact
    l = (unsigned short)(__float_as_uint(lf) >> 16);
}

// ---------------------------------------------------------------------------
// Kernel 0: precompute (x, y, z, |x|^2) per point for the KNN kernel,
// PLUS zero all 13 stats stages. sq formula matches numpy bit-for-bit.
// ---------------------------------------------------------------------------
__global__ __launch_bounds__(256) void prep_kernel(
        const float* __restrict__ xyz, float4* __restrict__ pts4g,
        float* __restrict__ stats) {
#pragma clang fp contract(off)
    int g = blockIdx.x * 256 + threadIdx.x;      // 0..32767
    if (g < 13 * NREP * 128) stats[g] = 0.0f;
    int b = g >> 12, j = g & 4095;
    const float* xb = xyz + (size_t)b * 3 * NPTS;
    float x = xb[j];
    float y = xb[NPTS + j];
    float z = xb[2 * NPTS + j];
    float sq = (x * x + y * y) + z * z;
    pts4g[g] = make_float4(x, y, z, sq);
}

// ---------------------------------------------------------------------------
// Kernel 1: transpose fp32 points [b][d][n] -> point-major P0[b][n][d],
// fused with stats[0] accumulation. XCD-affine: b = blockIdx & 7.
// Grid: 512 WGs, 256 threads.
// ---------------------------------------------------------------------------
__global__ __launch_bounds__(256) void cast_kernel(
        const float* __restrict__ pts,
        float* __restrict__ P0, float* __restrict__ stats0) {
    __shared__ __align__(16) float tr[64 * 65];      // [d][n] transpose tile (+1 pad)
    __shared__ float slotA[4 * 64], slotB[4 * 64];
    int wg = blockIdx.x;
    int b = wg & 7;                  // XCD affinity
    int n0 = (wg >> 3) << 6;
    int rep = (wg >> 3) & (NREP - 1);
    int tid = threadIdx.x;
    int lane6 = tid & 63;
    int grp = tid >> 6;              // 0..3

    #pragma unroll
    for (int k = 0; k < 16; ++k) {
        int d = grp + (k << 2);
        float v = pts[(((size_t)((b << 6) + d)) << 12) + n0 + lane6];
        tr[d * 65 + lane6] = v;
    }
    __syncthreads();
    int c = lane6;
    float s = 0.0f, s2 = 0.0f;
    #pragma unroll
    for (int k = 0; k < 16; ++k) {
        int p = grp + (k << 2);
        float v = tr[c * 65 + p];
        P0[((size_t)((b << 12) + n0 + p)) * 64 + c] = v;
        s += v; s2 += v * v;
    }
    slotA[grp * 64 + c] = s;
    slotB[grp * 64 + c] = s2;
    __syncthreads();
    if (tid < 64) {
        float t = slotA[tid] + slotA[64 + tid] + slotA[128 + tid] + slotA[192 + tid];
        atomicAdd(&stats0[rep * 128 + tid], t);
    } else if (tid < 128) {
        int cc = tid - 64;
        float t = slotB[cc] + slotB[64 + cc] + slotB[128 + cc] + slotB[192 + cc];
        atomicAdd(&stats0[rep * 128 + 64 + cc], t);
    }
}

// ---------------------------------------------------------------------------
// Kernel 2: brute-force 8-NN — EXACT R5 form (verified, 111-114 us).
// Scalar-fetch via readfirstlane; no LDS candidate staging; bit-exact d2;
// unique f64 keys (idx in low 12 mantissa bits).
// Grid: 8 b x 32 q-tiles of 128 = 256 WGs, 512 threads.
// ---------------------------------------------------------------------------
#define INS(KEY) do { \
    double key = (KEY); \
    double n0 = fmin(k0, key); \
    double n1 = fmin(k1, fmax(k0, key)); \
    double n2 = fmin(k2, fmax(k1, key)); \
    double n3 = fmin(k3, fmax(k2, key)); \
    double n4 = fmin(k4, fmax(k3, key)); \
    double n5 = fmin(k5, fmax(k4, key)); \
    double n6 = fmin(k6, fmax(k5, key)); \
    double n7 = fmin(k7, fmax(k6, key)); \
    k0 = n0; k1 = n1; k2 = n2; k3 = n3; \
    k4 = n4; k5 = n5; k6 = n6; k7 = n7; } while (0)

__global__ __launch_bounds__(512) void knn_kernel(
        const float4* __restrict__ pts4g, int* __restrict__ idx) {
#pragma clang fp contract(off)
    __shared__ double stash[4 * 9 * 128];            // 36 KB
    int wg = blockIdx.x;
    int b = wg >> 5;
    int q0 = (wg & 31) << 7;
    int tid = threadIdx.x;                           // 0..511

    int lane  = tid & 63;
    int wave  = tid >> 6;            // 0..7
    int chunk = wave & 3;
    int qgrp  = wave >> 2;           // 0..1
    int q_l   = (qgrp << 6) | lane;  // 0..127

    const float4* cb = pts4g + ((size_t)b << 12);
    float4 qp = cb[q0 + q_l];

    double k0, k1, k2, k3, k4, k5, k6, k7;
    k0 = k1 = k2 = k3 = k4 = k5 = k6 = k7 = __builtin_inf();
    float bd7f = 3.4e38f;

    int chu = __builtin_amdgcn_readfirstlane(chunk);
    const float4* cc = cb + ((size_t)chu << 10);     // this wave's 1024-cand window
    int jg0 = chu << 10;                             // global candidate index base

    // --- direct phase: first 128 candidates of the chunk, unconditional ---
    for (int jo = 0; jo < 128; jo += 8) {
        float d2v[8];
        #pragma unroll
        for (int u = 0; u < 8; ++u) {
            float4 p = cc[jo + u];                   // uniform -> s_load
            float dot = (qp.x * p.x + qp.y * p.y) + qp.z * p.z;
            d2v[u] = (qp.w - 2.0f * dot) + p.w;
        }
        #pragma unroll
        for (int u = 0; u < 8; ++u) {
            unsigned long long kb =
                __double_as_longlong((double)d2v[u]) |
                (unsigned long long)(jg0 + jo + u);
            INS(__longlong_as_double(kb));
        }
    }
    bd7f = (float)k7;    // exact: idx bits << half-ulp of f32

    // --- queued phase: branchless hitmask + wave drain ---
    for (int jo = 128; jo < 1024; jo += 8) {
        float d2v[8];
        unsigned hm = 0u;
        #pragma unroll
        for (int u = 0; u < 8; ++u) {
            float4 p = cc[jo + u];                   // uniform -> s_load
            float dot = (qp.x * p.x + qp.y * p.y) + qp.z * p.z;
            float d2 = (qp.w - 2.0f * dot) + p.w;
            d2v[u] = d2;
            hm |= (d2 < bd7f) ? (1u << u) : 0u;
        }
        while (__any(hm != 0u)) {
            if (hm) {
                int u = __builtin_ctz(hm);
                hm &= hm - 1u;
                float t0 = (u & 1) ? d2v[1] : d2v[0];
                float t1 = (u & 1) ? d2v[3] : d2v[2];
                float t2 = (u & 1) ? d2v[5] : d2v[4];
                float t3 = (u & 1) ? d2v[7] : d2v[6];
                float s0 = (u & 2) ? t1 : t0;
                float s1 = (u & 2) ? t3 : t2;
                float d2 = (u & 4) ? s1 : s0;
                unsigned long long kb =
                    __double_as_longlong((double)d2) |
                    (unsigned long long)(jg0 + jo + u);
                INS(__longlong_as_double(kb));
            }
        }
        bd7f = (float)k7;
    }

    {
        double* S = &stash[(chunk * 9) * 128 + q_l];
        S[0 * 128] = k0; S[1 * 128] = k1; S[2 * 128] = k2; S[3 * 128] = k3;
        S[4 * 128] = k4; S[5 * 128] = k5; S[6 * 128] = k6; S[7 * 128] = k7;
        S[8 * 128] = __builtin_inf();    // merge guard
    }
    __syncthreads();

    // 4-way merge per query by key (threads 0..127)
    if (tid < 128) {
        int h0 = 0, h1 = 0, h2 = 0, h3 = 0;
        int* op = idx + ((size_t)(b * NPTS + q0 + tid)) * 8;
        #pragma unroll
        for (int t = 0; t < 8; ++t) {
            double b0 = stash[(0 * 9 + h0) * 128 + tid];
            double b1 = stash[(1 * 9 + h1) * 128 + tid];
            double b2 = stash[(2 * 9 + h2) * 128 + tid];
            double b3 = stash[(3 * 9 + h3) * 128 + tid];
            double best = b0; int bc = 0;
            if (b1 < best) { best = b1; bc = 1; }
            if (b2 < best) { best = b2; bc = 2; }
            if (b3 < best) { best = b3; bc = 3; }
            h0 += (bc == 0); h1 += (bc == 1);
            h2 += (bc == 2); h3 += (bc == 3);
            op[t] = (int)(__double_as_longlong(best) & 0xFFFULL);
        }
    }
}

// ---------------------------------------------------------------------------
// Kernel 3 (x12): one residual block. GEMM via MFMA (split-bf16):
//   - m and W stored as hi/lo bf16 planes (Dekker split; 3 MFMA products
//     hi*hi + hi*lo + lo*hi, fp32 accumulate -> rel err ~3e-5, final
//     output error <0.01 vs 0.186 threshold).
//   - m layout [pt][d] (gather's NATURAL orientation); W layout [o][d]
//     (conv_w's original layout). Both stride 72 bf16 (2-way b128 floor).
//   - mfma_f32_16x16x32_bf16; D mapping col=lane&15, row=4*(lane>>4)+reg
//     (HW-verified). A row = lane&15, B col = lane&15; k-slot order
//     cancels (A and B use the same k-bijection).
//   - per-thread LDS reads 128 -> 20 b128; GEMM VALU -> 24 MFMA/wave.
// This is the verified R9 kernel (284.8 us total), restored after the
// R10 (capacity-only occupancy), R11 (grid-side occupancy), and R12
// (K'=576 global-A MFMA) experiments all came back neutral-to-regressed.
// Grid: 512 WGs (64 tiles x 8 b), 256 threads. LDS ~58 KB -> 2 WG/CU.
// ---------------------------------------------------------------------------
#define AH_OFF 0
#define AL_OFF (64 * 72)
#define WH_OFF (2 * 64 * 72)
#define WL_OFF (3 * 64 * 72)

__global__ __launch_bounds__(256) void block_kernel(
        const float* __restrict__ Pin, float* __restrict__ Pout,
        const float* __restrict__ statsIn, float* __restrict__ statsOut,
        const float* __restrict__ Wp, const float* __restrict__ Bp,
        const float* __restrict__ Gp, const float* __restrict__ Betap,
        const int* __restrict__ gidx, float* __restrict__ dout, int last) {
    __shared__ __align__(16) unsigned short planes[4 * 64 * 72]; // Ah|Al|Wh|Wl, 36 KB
    __shared__ __align__(16) float selft[64 * 64];   // raw self rows [pt][c]
    __shared__ __align__(16) int   idxl[64 * 8];
    __shared__ __align__(16) float scale_l[64], shift_l[64], bias_l[64];
    __shared__ float slot[4 * 128];

    int wg = blockIdx.x;
    int b = wg & 7;                  // XCD affinity
    int n0 = (wg >> 3) << 6;
    int rep = (wg >> 3) & (NREP - 1);
    int tid = threadIdx.x;

    const float* Pb = Pin + (((size_t)b) << 18);     // batch slice [4096][64]

    // --- setup: idx tile, self tile, W hi/lo planes, BN affine ---
    if (tid < 128) {
        ((int4*)idxl)[tid] = ((const int4*)(gidx + ((size_t)(b * NPTS + n0)) * 8))[tid];
    }
    #pragma unroll
    for (int k = 0; k < 4; ++k) {    // self rows: 64 pts x 64 ch, coalesced
        int lin = tid + (k << 8);    // float4 id
        ((float4*)selft)[lin] = ((const float4*)&Pb[(size_t)n0 << 6])[lin];
    }
    #pragma unroll
    for (int k = 0; k < 4; ++k) {    // W: 1024 float4 reads, split to bf16 planes
        int lin = tid + (k << 8);    // 0..1023
        float4 wv = ((const float4*)Wp)[lin];
        int o = lin >> 4, d4 = (lin & 15) << 2;
        unsigned short hx, hy, hz, hw, lx, ly, lz, lw;
        bsplit(wv.x, hx, lx); bsplit(wv.y, hy, ly);
        bsplit(wv.z, hz, lz); bsplit(wv.w, hw, lw);
        *(ushort4*)&planes[WH_OFF + o * 72 + d4] = make_ushort4(hx, hy, hz, hw);
        *(ushort4*)&planes[WL_OFF + o * 72 + d4] = make_ushort4(lx, ly, lz, lw);
    }
    if (tid < 64) {
        int c = tid;
        float sum = 0.0f, sumsq = 0.0f;
        #pragma unroll
        for (int r = 0; r < NREP; ++r) {
            sum   += statsIn[r * 128 + c];
            sumsq += statsIn[r * 128 + 64 + c];
        }
        float mean = sum * (1.0f / 32768.0f);
        float var  = sumsq * (1.0f / 32768.0f) - mean * mean;
        float rs   = 1.0f / sqrtf(var + 1e-5f);
        float sc   = Gp[c] * rs;
        scale_l[c] = sc;
        shift_l[c] = Betap[c] - mean * sc;
        bias_l[c]  = Bp[c];
    }
    __syncthreads();

    // --- gather: m[pt][c4..c4+3] -> hi/lo bf16 planes (natural layout) ---
    {
        int cq = tid & 15;           // channel quad: channels 4cq..4cq+3
        int pg = tid >> 4;           // 0..15: points 4pg..4pg+3
        int c4 = cq << 2;
        float4 sc4 = *(const float4*)&scale_l[c4];
        float4 sh4 = *(const float4*)&shift_l[c4];
        #pragma unroll
        for (int i = 0; i < 4; ++i) {
            int pt = (pg << 2) + i;
            int4 ja = *(const int4*)&idxl[pt * 8];
            int4 jb = *(const int4*)&idxl[pt * 8 + 4];
            float4 v[9];
            v[0] = *(const float4*)&selft[(pt << 6) + c4];
            v[1] = *(const float4*)&Pb[(((size_t)ja.x) << 6) + c4];
            v[2] = *(const float4*)&Pb[(((size_t)ja.y) << 6) + c4];
            v[3] = *(const float4*)&Pb[(((size_t)ja.z) << 6) + c4];
            v[4] = *(const float4*)&Pb[(((size_t)ja.w) << 6) + c4];
            v[5] = *(const float4*)&Pb[(((size_t)jb.x) << 6) + c4];
            v[6] = *(const float4*)&Pb[(((size_t)jb.y) << 6) + c4];
            v[7] = *(const float4*)&Pb[(((size_t)jb.z) << 6) + c4];
            v[8] = *(const float4*)&Pb[(((size_t)jb.w) << 6) + c4];
            float4 a = make_float4(0.f, 0.f, 0.f, 0.f);
            #pragma unroll
            for (int k = 0; k < 9; ++k) {
                float hx = v[k].x * sc4.x + sh4.x;
                float hy = v[k].y * sc4.y + sh4.y;
                float hz = v[k].z * sc4.z + sh4.z;
                float hw = v[k].w * sc4.w + sh4.w;
                a.x += fmaxf(hx, 0.01f * hx);
                a.y += fmaxf(hy, 0.01f * hy);
                a.z += fmaxf(hz, 0.01f * hz);
                a.w += fmaxf(hw, 0.01f * hw);
            }
            float mx = a.x * (1.0f / 9.0f), my = a.y * (1.0f / 9.0f);
            float mz = a.z * (1.0f / 9.0f), mw = a.w * (1.0f / 9.0f);
            unsigned short hx2, hy2, hz2, hw2, lx2, ly2, lz2, lw2;
            bsplit(mx, hx2, lx2); bsplit(my, hy2, ly2);
            bsplit(mz, hz2, lz2); bsplit(mw, hw2, lw2);
            *(ushort4*)&planes[AH_OFF + pt * 72 + c4] = make_ushort4(hx2, hy2, hz2, hw2);
            *(ushort4*)&planes[AL_OFF + pt * 72 + c4] = make_ushort4(lx2, ly2, lz2, lw2);
        }
    }
    __syncthreads();

    // --- GEMM via MFMA: wave w -> pt rows [16w,16w+16), all 64 o ---
    int lane = tid & 63;
    int w    = tid >> 6;             // 0..3
    int g    = lane >> 4;            // k-group
    int c    = lane & 15;
    int ptb  = w << 4;

    short8 a_h[2], a_l[2];
    #pragma unroll
    for (int s = 0; s < 2; ++s) {
        int off = (ptb + c) * 72 + (s << 5) + (g << 3);
        a_h[s] = *(const short8*)&planes[AH_OFF + off];
        a_l[s] = *(const short8*)&planes[AL_OFF + off];
    }

    f32x4 out[4];
    #pragma unroll
    for (int ot = 0; ot < 4; ++ot) {
        int co = (ot << 4) + c;
        short8 b_h[2], b_l[2];
        #pragma unroll
        for (int s = 0; s < 2; ++s) {
            int off = co * 72 + (s << 5) + (g << 3);
            b_h[s] = *(const short8*)&planes[WH_OFF + off];
            b_l[s] = *(const short8*)&planes[WL_OFF + off];
        }
        f32x4 acc = {0.f, 0.f, 0.f, 0.f};
        acc = __builtin_amdgcn_mfma_f32_16x16x32_bf16(a_h[0], b_h[0], acc, 0, 0, 0);
        acc = __builtin_amdgcn_mfma_f32_16x16x32_bf16(a_h[1], b_h[1], acc, 0, 0, 0);
        acc = __builtin_amdgcn_mfma_f32_16x16x32_bf16(a_h[0], b_l[0], acc, 0, 0, 0);
        acc = __builtin_amdgcn_mfma_f32_16x16x32_bf16(a_h[1], b_l[1], acc, 0, 0, 0);
        acc = __builtin_amdgcn_mfma_f32_16x16x32_bf16(a_l[0], b_h[0], acc, 0, 0, 0);
        acc = __builtin_amdgcn_mfma_f32_16x16x32_bf16(a_l[1], b_h[1], acc, 0, 0, 0);
        out[ot] = acc;
    }

    // --- epilogue: + bias + residual; D lane holds col=16ot+c, row=4g+j ---
    #pragma unroll
    for (int ot = 0; ot < 4; ++ot) {
        int co = (ot << 4) + c;
        float bv = bias_l[co];
        #pragma unroll
        for (int j = 0; j < 4; ++j) {
            int pt = ptb + (g << 2) + j;
            out[ot][j] += bv + selft[(pt << 6) + co];
        }
    }

    if (!last) {
        float* PbOut = Pout + ((((size_t)b) << 12) + n0) * 64;
        #pragma unroll
        for (int j = 0; j < 4; ++j) {
            int pt = ptb + (g << 2) + j;
            #pragma unroll
            for (int ot = 0; ot < 4; ++ot)
                PbOut[(size_t)pt * 64 + (ot << 4) + c] = out[ot][j];
        }

        // --- stats: j-sum (4 pts) then xor over g -> wave col-sums ---
        float sv[4], qv[4];
        #pragma unroll
        for (int ot = 0; ot < 4; ++ot) {
            float s = 0.f, q = 0.f;
            #pragma unroll
            for (int j = 0; j < 4; ++j) {
                float v = out[ot][j];
                s += v; q += v * v;
            }
            sv[ot] = s; qv[ot] = q;
        }
        #pragma unroll
        for (int m = 16; m <= 32; m <<= 1) {
            #pragma unroll
            for (int ot = 0; ot < 4; ++ot) {
                sv[ot] += __shfl_xor(sv[ot], m, 64);
                qv[ot] += __shfl_xor(qv[ot], m, 64);
            }
        }
        if (lane < 16) {
            #pragma unroll
            for (int ot = 0; ot < 4; ++ot) {
                slot[w * 128 + (ot << 4) + lane]      = sv[ot];
                slot[w * 128 + 64 + (ot << 4) + lane] = qv[ot];
            }
        }
        __syncthreads();
        if (tid < 128) {
            float t = slot[tid] + slot[128 + tid] + slot[256 + tid] + slot[384 + tid];
            atomicAdd(&statsOut[rep * 128 + tid], t);
        }
    } else {
        __syncthreads();                         // all plane reads done
        float* stage = (float*)planes;           // reuse as [o][pt] (65-pad), 16.6 KB
        #pragma unroll
        for (int ot = 0; ot < 4; ++ot) {
            int co = (ot << 4) + c;
            #pragma unroll
            for (int j = 0; j < 4; ++j)
                stage[co * 65 + ptb + (g << 2) + j] = out[ot][j];
        }
        __syncthreads();
        #pragma unroll
        for (int k = 0; k < 16; ++k) {
            int lin = tid + (k << 8);
            int o = lin >> 6, pt = lin & 63;
            dout[(((size_t)((b << 6) + o)) << 12) + n0 + pt] = stage[o * 65 + pt];
        }
    }
}

// ---------------------------------------------------------------------------
extern "C" void kernel_launch(void* const* d_in, const int* in_sizes, int n_in,
                              void* d_out, int out_size, void* d_ws, size_t ws_size,
                              hipStream_t stream) {
    const float* xyz    = (const float*)d_in[0];
    const float* pts    = (const float*)d_in[1];
    const float* conv_w = (const float*)d_in[2];
    const float* conv_b = (const float*)d_in[3];
    const float* gamma  = (const float*)d_in[4];
    const float* beta   = (const float*)d_in[5];
    float* out = (float*)d_out;

    char* ws = (char*)d_ws;
    float*  P0    = (float*)(ws);                                  //  8 MB
    float*  P1    = (float*)(ws + (size_t)8 * 1024 * 1024);        //  8 MB
    int*    idx   = (int*)  (ws + (size_t)16 * 1024 * 1024);       //  1 MB
    float*  stats = (float*)(ws + (size_t)17 * 1024 * 1024);       // 52 KB
    float4* pts4g = (float4*)(ws + (size_t)18 * 1024 * 1024);      // 512 KB

    prep_kernel<<<128, 256, 0, stream>>>(xyz, pts4g, stats);
    cast_kernel<<<512, 256, 0, stream>>>(pts, P0, stats);
    knn_kernel<<<256, 512, 0, stream>>>(pts4g, idx);

    float* Pbuf[2] = {P0, P1};
    for (int t = 0; t < NBLK; ++t) {
        block_kernel<<<512, 256, 0, stream>>>(
            Pbuf[t & 1], Pbuf[(t + 1) & 1],
            stats + (size_t)t * NREP * 128, stats + (size_t)(t + 1) * NREP * 128,
            conv_w + (size_t)t * 4096, conv_b + (size_t)t * 64,
            gamma + (size_t)t * 64, beta + (size_t)t * 64,
            idx, out, (t == NBLK - 1) ? 1 : 0);
    }
}